// Round 4
// baseline (831.087 us; speedup 1.0000x reference)
//
#include <hip/hip_runtime.h>

#define N_NODES 100000
#define N_EDGES 1600000
#define DIM     64
#define HID     256
#define BN_EPS  1e-5f

// counting-sort parameters
#define NBUCK   391            // ceil(100000/256) buckets of 256 nodes
#define RSTRIDE 392            // runoff row stride (NBUCK + 1 for chunk total)
#define SCHUNK  3125           // edges per kA_scatter block
#define SBLK    512            // 512 * 3125 = 1,600,000 exactly
#define MAXB    6144           // max edges per bucket (mean 4092, sd 64)

// MLP parameters
#define XBROWS  100032         // padded xb rows
#define NGP     782            // ceil(100032/128) block-iterations of 128 rows
#define MLPGRID 256            // 1 block/CU (LDS-forced); grid == CU count
#define MAXIT   4              // ceil(NGP/MLPGRID)

typedef short bf16x8 __attribute__((ext_vector_type(8)));
typedef float f32x4  __attribute__((ext_vector_type(4)));

// ws layout (4-byte units):
//   stats   float[128]         @ 0        (sum[64], sumsq[64])   [zeroed]
//   bar     int[128]           @ 128      (grid barrier)         [zeroed]
//   runoff  int[512*392]       @ 256      (200704; dead after kB_agg -> dump)
//   w1t_g   bf16[256*64]       @ 200960   (8192 ints) [n][k] chunk-swizzled
//   w2t_g   bf16[64*256]       @ 209152   (8192 ints) [d][k2] chunk-swizzled
//   xb      bf16[100032*64]    @ 217344   (3201024 ints, 16B aligned)
//   ebuf    u32[1600000]       @ 3418368
//   hb      bf16[100000*64]    @ 5018368  (3200000 ints) h in bf16 row-major
// memset covers stats+bar = 1024 B @ 0

__device__ __forceinline__ unsigned short f2bf(float x) {
    unsigned int u = __float_as_uint(x);
    unsigned int r = (u + 0x7FFFu + ((u >> 16) & 1u)) >> 16;
    return (unsigned short)r;
}

#define WAITV(N) asm volatile("s_waitcnt vmcnt(" #N ")" ::: "memory")

// issue 2x global_load_lds(16B) staging 16 rows (2048 B) into per-wave LDS buffer.
__device__ __forceinline__ void stage_issue(const unsigned short* gsrc,
                                            unsigned short* ldst) {
    __builtin_amdgcn_global_load_lds(
        (const __attribute__((address_space(1))) void*)gsrc,
        (__attribute__((address_space(3))) void*)ldst, 16, 0, 0);
    __builtin_amdgcn_global_load_lds(
        (const __attribute__((address_space(1))) void*)(gsrc + 512),
        (__attribute__((address_space(3))) void*)(ldst + 512), 16, 0, 0);
}

// ---------------------------------------------------------------------------
// Pass A: per-chunk LDS counting sort by coarse bucket (dst>>8).
// 512 blocks x 3125 edges: all 256 CUs busy at 2 blocks/CU.
// ---------------------------------------------------------------------------
__global__ __launch_bounds__(1024) void kA_scatter(const int* __restrict__ src,
                                                   const int* __restrict__ dst,
                                                   unsigned int* __restrict__ ebuf,
                                                   int* __restrict__ runoff) {
    __shared__ int hist[NBUCK];
    __shared__ int ebase[NBUCK];
    __shared__ int sc[512];
    __shared__ unsigned int stage[SCHUNK];
    const int t = threadIdx.x;
    const int e0 = blockIdx.x * SCHUNK;
    const int n = SCHUNK;                         // exact partition

    for (int i = t; i < NBUCK; i += 1024) hist[i] = 0;
    __syncthreads();
    for (int i = t; i < n; i += 1024)
        atomicAdd(&hist[dst[e0 + i] >> 8], 1);
    __syncthreads();

    if (t < 512) sc[t] = (t < NBUCK) ? hist[t] : 0;
    __syncthreads();
    for (int off = 1; off < 512; off <<= 1) {
        int add = (t < 512 && t >= off) ? sc[t - off] : 0;
        __syncthreads();
        if (t < 512) sc[t] += add;
        __syncthreads();
    }
    if (t < NBUCK) {
        int ex = sc[t] - hist[t];
        ebase[t] = ex;
        runoff[blockIdx.x * RSTRIDE + t] = ex;
    }
    if (t == 0) runoff[blockIdx.x * RSTRIDE + NBUCK] = n;
    if (t < NBUCK) hist[t] = 0;
    __syncthreads();

    for (int i = t; i < n; i += 1024) {
        int d = dst[e0 + i];
        int s = src[e0 + i];
        int b = d >> 8;
        int r = atomicAdd(&hist[b], 1);
        stage[ebase[b] + r] = ((unsigned int)s << 8) | (unsigned int)(d & 255);
    }
    __syncthreads();
    for (int i = t; i < n; i += 1024)
        ebuf[e0 + i] = stage[i];
}

// ---------------------------------------------------------------------------
// Pass B (fused): one block per bucket. Gather bucket edges, accumulate
// hb[src] rows into padded LDS f32 accumulator via ds_add_f32, count degree,
// emit xb = acc/max(deg,1) + own  (chunk-swizzled bf16 rows). No CSR.
// LDS: 2052+2048+2048+24576+65568+1024 = 97316 B -> 1 block/CU, 16 waves.
// ---------------------------------------------------------------------------
__global__ __launch_bounds__(1024) void kB_agg(const unsigned int* __restrict__ ebuf,
                                               const int* __restrict__ runoff,
                                               const unsigned short* __restrict__ hb,
                                               unsigned short* __restrict__ xb) {
    __shared__ int runbase[SBLK + 1];
    __shared__ int runstart[SBLK];
    __shared__ int sc[SBLK];
    __shared__ unsigned int stage2[MAXB];
    __shared__ float sacc[8 * 2049];   // plane c: [2049] pad -> ~2-way ds_add banks
    __shared__ int cnt[256];
    const int t = threadIdx.x;
    const int b = blockIdx.x;

    int rl = 0;
    if (t < SBLK) {
        int s = runoff[t * RSTRIDE + b];
        int e = runoff[t * RSTRIDE + b + 1];
        runstart[t] = t * SCHUNK + s;
        rl = e - s;
        sc[t] = rl;
    }
    for (int i = t; i < 8 * 2049; i += 1024) sacc[i] = 0.f;
    if (t < 256) cnt[t] = 0;
    __syncthreads();
    for (int o = 1; o < SBLK; o <<= 1) {
        int add = (t < SBLK && t >= o) ? sc[t - o] : 0;
        __syncthreads();
        if (t < SBLK) sc[t] += add;
        __syncthreads();
    }
    if (t < SBLK) runbase[t] = sc[t] - rl;
    if (t == 0) runbase[SBLK] = sc[SBLK - 1];
    __syncthreads();
    const int total = min(runbase[SBLK], MAXB);

    // gather this bucket's edges into LDS (coalesced per run) + degree count
    for (int idx = t; idx < total; idx += 1024) {
        int lo = 0, hi = SBLK - 1;
        while (lo < hi) {
            int mid = (lo + hi + 1) >> 1;
            if (runbase[mid] <= idx) lo = mid; else hi = mid - 1;
        }
        unsigned int v = ebuf[runstart[lo] + (idx - runbase[lo])];
        stage2[idx] = v;
        atomicAdd(&cnt[v & 255u], 1);
    }
    __syncthreads();

    // aggregate: 8-lane group per edge; lane c covers dims c*8..c*8+7.
    const int g = t >> 3, c = t & 7;
    const unsigned short* hc = hb + c * 8;
    float* accp = &sacc[c * 2049];
    for (int i = g; i < total; i += 128) {
        unsigned int v = stage2[i];
        int node = (int)(v & 255u);
        int srcn = (int)(v >> 8);
        uint4 hv = *(const uint4*)&hc[(size_t)srcn * 64];
        float* ap = accp + node * 8;
        atomicAdd(ap + 0, __uint_as_float(hv.x << 16));
        atomicAdd(ap + 1, __uint_as_float(hv.x & 0xffff0000u));
        atomicAdd(ap + 2, __uint_as_float(hv.y << 16));
        atomicAdd(ap + 3, __uint_as_float(hv.y & 0xffff0000u));
        atomicAdd(ap + 4, __uint_as_float(hv.z << 16));
        atomicAdd(ap + 5, __uint_as_float(hv.z & 0xffff0000u));
        atomicAdd(ap + 6, __uint_as_float(hv.w << 16));
        atomicAdd(ap + 7, __uint_as_float(hv.w & 0xffff0000u));
    }
    __syncthreads();

    // emit: 128 groups x 2 passes over the 256 nodes of this bucket
    const int gn0 = b * 256;
#pragma unroll
    for (int pass = 0; pass < 2; ++pass) {
        int nloc = pass * 128 + g;
        int gnode = gn0 + nloc;
        if (gnode < N_NODES) {
            const float* ap = accp + nloc * 8;
            float inv = 1.0f / (float)max(cnt[nloc], 1);
            uint4 ov = *(const uint4*)&hc[(size_t)gnode * 64];
            float x0 = fmaf(ap[0], inv, __uint_as_float(ov.x << 16));
            float x1 = fmaf(ap[1], inv, __uint_as_float(ov.x & 0xffff0000u));
            float x2 = fmaf(ap[2], inv, __uint_as_float(ov.y << 16));
            float x3 = fmaf(ap[3], inv, __uint_as_float(ov.y & 0xffff0000u));
            float x4 = fmaf(ap[4], inv, __uint_as_float(ov.z << 16));
            float x5 = fmaf(ap[5], inv, __uint_as_float(ov.z & 0xffff0000u));
            float x6 = fmaf(ap[6], inv, __uint_as_float(ov.w << 16));
            float x7 = fmaf(ap[7], inv, __uint_as_float(ov.w & 0xffff0000u));
            uint4 o;
            o.x = (unsigned)f2bf(x0) | ((unsigned)f2bf(x1) << 16);
            o.y = (unsigned)f2bf(x2) | ((unsigned)f2bf(x3) << 16);
            o.z = (unsigned)f2bf(x4) | ((unsigned)f2bf(x5) << 16);
            o.w = (unsigned)f2bf(x6) | ((unsigned)f2bf(x7) << 16);
            *(uint4*)&xb[(size_t)gnode * 64 + ((c ^ (gnode & 7)) << 3)] = o;
        }
    }
}

// weight prep (chunk-swizzled) + xb pad zero + h -> bf16 hb conversion
__global__ __launch_bounds__(256) void k_wprep(const float* __restrict__ W1,
                                               const float* __restrict__ W2,
                                               const float* __restrict__ h,
                                               unsigned short* __restrict__ w1t,
                                               unsigned short* __restrict__ w2t,
                                               unsigned short* __restrict__ xb,
                                               unsigned short* __restrict__ hb) {
    int id = blockIdx.x * 256 + threadIdx.x;     // 3261*256 = 834816
    if (id < 16384) {                            // n*64+k
        int n = id >> 6, k = id & 63;
        int dstp = (n << 6) + ((((k >> 3) ^ (n & 7))) << 3) + (k & 7);
        w1t[dstp] = f2bf(W1[k * 256 + n]);
    } else if (id < 32768) {
        int i2 = id - 16384;                     // d*256+k2
        int d = i2 >> 8, k2 = i2 & 255;
        int dstp = (d << 8) + ((((k2 >> 3) ^ (d & 7))) << 3) + (k2 & 7);
        w2t[dstp] = f2bf(W2[k2 * 64 + d]);
    } else if (id < 34816) {                     // zero 32 pad rows of xb
        xb[100000 * 64 + (id - 32768)] = 0;
    } else {                                     // h -> bf16, 8 elems/thread
        int i = id - 34816;                      // < 800000
        int e = i * 8;
        float4 f0 = *(const float4*)&h[e];
        float4 f1 = *(const float4*)&h[e + 4];
        uint4 o;
        o.x = (unsigned)f2bf(f0.x) | ((unsigned)f2bf(f0.y) << 16);
        o.y = (unsigned)f2bf(f0.z) | ((unsigned)f2bf(f0.w) << 16);
        o.z = (unsigned)f2bf(f1.x) | ((unsigned)f2bf(f1.y) << 16);
        o.w = (unsigned)f2bf(f1.z) | ((unsigned)f2bf(f1.w) << 16);
        *(uint4*)&hb[e] = o;
    }
}

// ---------------------------------------------------------------------------
// Fused MLP core (unchanged)
// ---------------------------------------------------------------------------
__device__ __forceinline__ void mlp_tile(const unsigned short* sXw,
                                         const unsigned short* sW1,
                                         const unsigned short* sW2,
                                         unsigned short* sHw,
                                         const float* sB1,
                                         int l15, int g4, int s7,
                                         f32x4 oacc[4]) {
    bf16x8 xf0 = *(const bf16x8*)&sXw[l15 * 64 + ((g4 ^ s7) << 3)];
    bf16x8 xf1 = *(const bf16x8*)&sXw[l15 * 64 + (((g4 + 4) ^ s7) << 3)];
#pragma unroll
    for (int dt = 0; dt < 4; ++dt) oacc[dt] = (f32x4){0.f, 0.f, 0.f, 0.f};

#pragma unroll
    for (int p = 0; p < 4; ++p) {
#pragma unroll
        for (int nt2 = 0; nt2 < 4; ++nt2) {
            const int n0 = p * 64 + nt2 * 16;
            f32x4 hacc = (f32x4){0.f, 0.f, 0.f, 0.f};
            bf16x8 wf0 = *(const bf16x8*)&sW1[(n0 + l15) * 64 + ((g4 ^ s7) << 3)];
            bf16x8 wf1 = *(const bf16x8*)&sW1[(n0 + l15) * 64 + (((g4 + 4) ^ s7) << 3)];
            hacc = __builtin_amdgcn_mfma_f32_16x16x32_bf16(wf0, xf0, hacc, 0, 0, 0);
            hacc = __builtin_amdgcn_mfma_f32_16x16x32_bf16(wf1, xf1, hacc, 0, 0, 0);
            float4 bq = *(const float4*)&sB1[n0 + g4 * 4];
            ushort4 pk;
            pk.x = f2bf(fmaxf(hacc[0] + bq.x, 0.f));
            pk.y = f2bf(fmaxf(hacc[1] + bq.y, 0.f));
            pk.z = f2bf(fmaxf(hacc[2] + bq.z, 0.f));
            pk.w = f2bf(fmaxf(hacc[3] + bq.w, 0.f));
            int qh = nt2 * 2 + (g4 >> 1);
            *(ushort4*)&sHw[l15 * 64 + ((qh ^ s7) << 3) + ((g4 & 1) << 2)] = pk;
        }
#pragma unroll
        for (int s2 = 0; s2 < 2; ++s2) {
            bf16x8 a2 = *(const bf16x8*)&sHw[l15 * 64 + (((s2 * 4 + g4) ^ s7) << 3)];
#pragma unroll
            for (int dt = 0; dt < 4; ++dt) {
                int q = p * 8 + s2 * 4 + g4;
                bf16x8 w2f = *(const bf16x8*)&sW2[(dt * 16 + l15) * 256 + ((q ^ s7) << 3)];
                oacc[dt] = __builtin_amdgcn_mfma_f32_16x16x32_bf16(a2, w2f, oacc[dt], 0, 0, 0);
            }
        }
    }
}

// single-pass MLP + BN (grid barrier; all 256 blocks co-resident)
__global__ __launch_bounds__(512, 2) void k_mlpf(const unsigned short* __restrict__ xb,
                                                 const unsigned short* __restrict__ w1t,
                                                 const unsigned short* __restrict__ w2t,
                                                 const float* __restrict__ b1,
                                                 const float* __restrict__ b2,
                                                 const float* __restrict__ gamma,
                                                 const float* __restrict__ beta,
                                                 float* __restrict__ stats,
                                                 int* __restrict__ bar,
                                                 float* __restrict__ out,
                                                 float* __restrict__ dump) {
    __shared__ unsigned short sW1[256 * 64];
    __shared__ unsigned short sW2[64 * 256];
    __shared__ unsigned short sH[8][16 * 64];
    __shared__ unsigned short sX[8][2][16 * 64];
    __shared__ float sB1[256];
    const int t = threadIdx.x;
    const int lane = t & 63;
    const int w = t >> 6;
    const int l15 = lane & 15;
    const int g4 = lane >> 4;
    const int s7 = l15 & 7;
    const int bid = blockIdx.x;

    for (int i = t; i < 2048; i += 512)
        *(uint4*)&sW1[i * 8] = *(const uint4*)&w1t[i * 8];
    for (int i = t; i < 2048; i += 512)
        *(uint4*)&sW2[i * 8] = *(const uint4*)&w2t[i * 8];
    if (t < 256) sB1[t] = b1[t];
    __syncthreads();

    float b2v[4];
#pragma unroll
    for (int dt = 0; dt < 4; ++dt) b2v[dt] = b2[dt * 16 + l15];

    float lsum[4] = {0.f, 0.f, 0.f, 0.f};
    float lsq[4]  = {0.f, 0.f, 0.f, 0.f};
    f32x4 osave[MAXIT][4];

    int cur = 0;
    {
        int r0 = min(bid * 128 + w * 16, XBROWS - 16);
        stage_issue(xb + (size_t)r0 * 64 + lane * 8, &sX[w][0][0]);
    }
#pragma unroll
    for (int it = 0; it < MAXIT; ++it) {
        int gp = bid + it * MLPGRID;
        int gpn = gp + MLPGRID; if (gpn >= NGP) gpn = gp;
        int r0n = min(gpn * 128 + w * 16, XBROWS - 16);
        stage_issue(xb + (size_t)r0n * 64 + lane * 8, &sX[w][cur ^ 1][0]);
        WAITV(2);
        __builtin_amdgcn_sched_barrier(0);
        const int row0 = gp * 128 + w * 16;
        if (gp < NGP && row0 < XBROWS) {
            f32x4 oacc[4];
            mlp_tile(&sX[w][cur][0], sW1, sW2, &sH[w][0], sB1, l15, g4, s7, oacc);
#pragma unroll
            for (int dt = 0; dt < 4; ++dt) {
#pragma unroll
                for (int r = 0; r < 4; ++r) {
                    float val = fmaxf(oacc[dt][r] + b2v[dt], 0.f);
                    osave[it][dt][r] = val;
                    int mabs = row0 + g4 * 4 + r;
                    if (mabs < N_NODES) {
                        lsum[dt] += val;
                        lsq[dt] += val * val;
                    }
                }
            }
        }
        cur ^= 1;
    }

    // block-level stats reduction (reuse sW1 memory)
    __syncthreads();
    float* sred = (float*)&sW1[0];                // [512][8] = 16 KB
#pragma unroll
    for (int dt = 0; dt < 4; ++dt) {
        sred[t * 8 + dt] = lsum[dt];
        sred[t * 8 + 4 + dt] = lsq[dt];
    }
    __syncthreads();
    if (t < 128) {
        int issq = (t >= 64) ? 4 : 0;
        int d = t & 63;
        int dt = d >> 4, dl = d & 15;
        float acc = 0.f;
        for (int i = 0; i < 32; ++i) acc += sred[(dl + 16 * i) * 8 + issq + dt];
        atomicAdd(&stats[(issq ? 64 : 0) + d], acc);
    }

    // software grid barrier
    __syncthreads();
    if (t == 0) {
        __hip_atomic_fetch_add(bar, 1, __ATOMIC_ACQ_REL, __HIP_MEMORY_SCOPE_AGENT);
        while (__hip_atomic_load(bar, __ATOMIC_ACQUIRE, __HIP_MEMORY_SCOPE_AGENT)
               < MLPGRID)
            __builtin_amdgcn_s_sleep(4);
    }
    __syncthreads();

    float scv[4], shv[4];
    const float inv_n = 1.0f / (float)N_NODES;
#pragma unroll
    for (int dt = 0; dt < 4; ++dt) {
        int d = dt * 16 + l15;
        float sm = __hip_atomic_load(&stats[d], __ATOMIC_RELAXED,
                                     __HIP_MEMORY_SCOPE_AGENT);
        float sq = __hip_atomic_load(&stats[64 + d], __ATOMIC_RELAXED,
                                     __HIP_MEMORY_SCOPE_AGENT);
        float m = sm * inv_n;
        float v = sq * inv_n - m * m;
        float sc = gamma[d] * rsqrtf(v + BN_EPS);
        scv[dt] = sc;
        shv[dt] = beta[d] - m * sc;
    }

#pragma unroll
    for (int it = 0; it < MAXIT; ++it) {
        int gp = bid + it * MLPGRID;
        const int row0 = gp * 128 + w * 16;
        if (gp >= NGP || row0 >= XBROWS) continue;
        float* sHf = (float*)&sH[w][0];           // [8][64] f32 = 2048 B
#pragma unroll
        for (int hh = 0; hh < 2; ++hh) {
            asm volatile("" ::: "memory");
            if ((g4 >> 1) == hh) {
#pragma unroll
                for (int dt = 0; dt < 4; ++dt) {
#pragma unroll
                    for (int r = 0; r < 4; ++r) {
                        float val = fmaf(osave[it][dt][r], scv[dt], shv[dt]);
                        sHf[((g4 & 1) * 4 + r) * 64 + dt * 16 + l15] = val;
                    }
                }
            }
            asm volatile("" ::: "memory");
#pragma unroll
            for (int j = 0; j < 2; ++j) {
                int rl = j * 4 + (lane >> 4);
                int rg = row0 + hh * 8 + rl;
                float4 v = *(const float4*)&sHf[rl * 64 + (lane & 15) * 4];
                float* dstp = (rg < N_NODES)
                    ? &out[(size_t)rg * 64 + (lane & 15) * 4]
                    : &dump[lane * 4];
                *(float4*)dstp = v;
            }
        }
    }
}

extern "C" void kernel_launch(void* const* d_in, const int* in_sizes, int n_in,
                              void* d_out, int out_size, void* d_ws, size_t ws_size,
                              hipStream_t stream) {
    const float* h     = (const float*)d_in[0];
    const float* W1    = (const float*)d_in[1];
    const float* b1    = (const float*)d_in[2];
    const float* W2    = (const float*)d_in[3];
    const float* b2    = (const float*)d_in[4];
    const float* gamma = (const float*)d_in[5];
    const float* beta  = (const float*)d_in[6];
    const int*   src   = (const int*)d_in[7];
    const int*   dst   = (const int*)d_in[8];

    int* wsi = (int*)d_ws;
    float*          stats = (float*)wsi;                           // 128
    int*            bar   = wsi + 128;                             // 128
    int*            runoff = wsi + 256;                            // 200704
    float*          dump  = (float*)(wsi + 256);                   // alias (dead)
    unsigned short* w1t   = (unsigned short*)(wsi + 200960);       // 8192 ints
    unsigned short* w2t   = (unsigned short*)(wsi + 209152);       // 8192 ints
    unsigned short* xb    = (unsigned short*)(wsi + 217344);       // 3201024 ints
    unsigned int*   ebuf  = (unsigned int*)(wsi + 3418368);        // 1600000
    unsigned short* hb    = (unsigned short*)(wsi + 5018368);      // 3200000 ints
    float*          out   = (float*)d_out;

    // zero stats + bar
    hipMemsetAsync(wsi, 0, 1024, stream);

    kA_scatter<<<SBLK, 1024, 0, stream>>>(src, dst, ebuf, runoff);
    k_wprep<<<3261, 256, 0, stream>>>(W1, W2, h, w1t, w2t, xb, hb);
    kB_agg<<<NBUCK, 1024, 0, stream>>>(ebuf, runoff, hb, xb);
    k_mlpf<<<MLPGRID, 512, 0, stream>>>(xb, w1t, w2t, b1, b2, gamma, beta,
                                        stats, bar, out, dump);
}

// Round 5
// 176.080 us; speedup vs baseline: 4.7200x; 4.7200x over previous
//
#include <hip/hip_runtime.h>

#define N_NODES 100000
#define N_EDGES 1600000
#define DIM     64
#define HID     256
#define BN_EPS  1e-5f

// counting-sort parameters
#define NBUCK   391            // ceil(100000/256) buckets of 256 nodes
#define RSTRIDE 392            // runoff row stride (NBUCK + 1 for chunk total)
#define SCHUNK  3125           // edges per kA_scatter block
#define SBLK    512            // 512 * 3125 = 1,600,000 exactly
#define MAXB    6144           // max edges per bucket (mean 4096, sd 64 -> +32 sd)

// MLP parameters
#define XBROWS  100032         // padded xb rows
#define NGP     782            // ceil(100032/128) block-iterations of 128 rows
#define MLPGRID 256            // 1 block/CU (LDS-forced); grid == CU count
#define MAXIT   4              // ceil(NGP/MLPGRID)

typedef short bf16x8 __attribute__((ext_vector_type(8)));
typedef float f32x4  __attribute__((ext_vector_type(4)));

// ws layout (4-byte units):
//   stats   float[128]         @ 0        (sum[64], sumsq[64])   [zeroed]
//   bar     int[128]           @ 128      (grid barrier)         [zeroed]
//   runoff  int[512*392]       @ 256      (200704; dead after kB_fused -> dump)
//   w1t_g   bf16[256*64]       @ 200960   (8192 ints) [n][k] chunk-swizzled
//   w2t_g   bf16[64*256]       @ 209152   (8192 ints) [d][k2] chunk-swizzled
//   xb      bf16[100032*64]    @ 217344   (3201024 ints, 16B aligned)
//   ebuf    u32[1600000]       @ 3418368
//   hb      bf16[100000*64]    @ 5018368  (3200000 ints) h in bf16 row-major
// memset covers stats+bar = 1024 B @ 0

__device__ __forceinline__ unsigned short f2bf(float x) {
    unsigned int u = __float_as_uint(x);
    unsigned int r = (u + 0x7FFFu + ((u >> 16) & 1u)) >> 16;
    return (unsigned short)r;
}

#define WAITV(N) asm volatile("s_waitcnt vmcnt(" #N ")" ::: "memory")

// issue 2x global_load_lds(16B) staging 16 rows (2048 B) into per-wave LDS buffer.
__device__ __forceinline__ void stage_issue(const unsigned short* gsrc,
                                            unsigned short* ldst) {
    __builtin_amdgcn_global_load_lds(
        (const __attribute__((address_space(1))) void*)gsrc,
        (__attribute__((address_space(3))) void*)ldst, 16, 0, 0);
    __builtin_amdgcn_global_load_lds(
        (const __attribute__((address_space(1))) void*)(gsrc + 512),
        (__attribute__((address_space(3))) void*)(ldst + 512), 16, 0, 0);
}

// ---------------------------------------------------------------------------
// Pass A: per-chunk LDS counting sort by coarse bucket (dst>>8).
// 512 blocks x 3125 edges: all 256 CUs busy at 2 blocks/CU.
// ---------------------------------------------------------------------------
__global__ __launch_bounds__(1024) void kA_scatter(const int* __restrict__ src,
                                                   const int* __restrict__ dst,
                                                   unsigned int* __restrict__ ebuf,
                                                   int* __restrict__ runoff) {
    __shared__ int hist[NBUCK];
    __shared__ int ebase[NBUCK];
    __shared__ int sc[512];
    __shared__ unsigned int stage[SCHUNK];
    const int t = threadIdx.x;
    const int e0 = blockIdx.x * SCHUNK;
    const int n = SCHUNK;                         // exact partition

    for (int i = t; i < NBUCK; i += 1024) hist[i] = 0;
    __syncthreads();
    for (int i = t; i < n; i += 1024)
        atomicAdd(&hist[dst[e0 + i] >> 8], 1);    // int LDS atomic: native ds op
    __syncthreads();

    if (t < 512) sc[t] = (t < NBUCK) ? hist[t] : 0;
    __syncthreads();
    for (int off = 1; off < 512; off <<= 1) {
        int add = (t < 512 && t >= off) ? sc[t - off] : 0;
        __syncthreads();
        if (t < 512) sc[t] += add;
        __syncthreads();
    }
    if (t < NBUCK) {
        int ex = sc[t] - hist[t];
        ebase[t] = ex;
        runoff[blockIdx.x * RSTRIDE + t] = ex;
    }
    if (t == 0) runoff[blockIdx.x * RSTRIDE + NBUCK] = n;
    if (t < NBUCK) hist[t] = 0;
    __syncthreads();

    for (int i = t; i < n; i += 1024) {
        int d = dst[e0 + i];
        int s = src[e0 + i];
        int b = d >> 8;
        int r = atomicAdd(&hist[b], 1);
        stage[ebase[b] + r] = ((unsigned int)s << 8) | (unsigned int)(d & 255);
    }
    __syncthreads();
    for (int i = t; i < n; i += 1024)
        ebuf[e0 + i] = stage[i];
}

// ---------------------------------------------------------------------------
// Pass B (fused, register-accumulate): one block per bucket.
// 1) gather bucket edges from 512 runs -> stage2 (LDS) + degree histogram
// 2) per-node offsets via LDS scan; sort src ids into sout (int LDS atomics)
// 3) 8-lane group per node: walk its contiguous sout segment, gather hb rows,
//    REGISTER-accumulate, emit xb = acc/max(deg,1)+own (swizzled bf16 row).
// No FP atomics anywhere. LDS ~58 KB -> 2 blocks/CU possible.
// ---------------------------------------------------------------------------
__global__ __launch_bounds__(1024) void kB_fused(const unsigned int* __restrict__ ebuf,
                                                 const int* __restrict__ runoff,
                                                 const unsigned short* __restrict__ hb,
                                                 unsigned short* __restrict__ xb) {
    __shared__ int runbase[SBLK + 1];
    __shared__ int runstart[SBLK];
    __shared__ int sc[SBLK];
    __shared__ int cnt[256];
    __shared__ int off[256];
    __shared__ unsigned int stage2[MAXB];
    __shared__ unsigned int sout[MAXB];
    const int t = threadIdx.x;
    const int b = blockIdx.x;

    int rl = 0;
    if (t < SBLK) {
        int s = runoff[t * RSTRIDE + b];
        int e = runoff[t * RSTRIDE + b + 1];
        runstart[t] = t * SCHUNK + s;
        rl = e - s;
        sc[t] = rl;
    }
    if (t < 256) cnt[t] = 0;
    __syncthreads();
    for (int o = 1; o < SBLK; o <<= 1) {
        int add = (t < SBLK && t >= o) ? sc[t - o] : 0;
        __syncthreads();
        if (t < SBLK) sc[t] += add;
        __syncthreads();
    }
    if (t < SBLK) runbase[t] = sc[t] - rl;
    if (t == 0) runbase[SBLK] = sc[SBLK - 1];
    __syncthreads();
    const int total = min(runbase[SBLK], MAXB);

    // gather this bucket's edges into LDS (coalesced per run) + degree count
    for (int idx = t; idx < total; idx += 1024) {
        int lo = 0, hi = SBLK - 1;
        while (lo < hi) {
            int mid = (lo + hi + 1) >> 1;
            if (runbase[mid] <= idx) lo = mid; else hi = mid - 1;
        }
        unsigned int v = ebuf[runstart[lo] + (idx - runbase[lo])];
        stage2[idx] = v;
        atomicAdd(&cnt[v & 255u], 1);
    }
    __syncthreads();

    // per-node exclusive offsets within the bucket
    int c0 = (t < 256) ? cnt[t] : 0;
    if (t < 256) sc[t] = c0;
    __syncthreads();
    for (int o = 1; o < 256; o <<= 1) {
        int add = (t < 256 && t >= o) ? sc[t - o] : 0;
        __syncthreads();
        if (t < 256) sc[t] += add;
        __syncthreads();
    }
    if (t < 256) { off[t] = sc[t] - c0; cnt[t] = 0; }
    __syncthreads();

    // sort src ids by node into sout (contiguous per-node segments)
    for (int idx = t; idx < total; idx += 1024) {
        unsigned int v = stage2[idx];
        int node = (int)(v & 255u);
        int r = atomicAdd(&cnt[node], 1);
        sout[off[node] + r] = v >> 8;
    }
    __syncthreads();

    // aggregate: 8-lane group per node; lane c covers dims c*8..c*8+7.
    const int g = t >> 3, c = t & 7;
    const unsigned short* hc = hb + c * 8;
    const int gn0 = b * 256;
#pragma unroll
    for (int pass = 0; pass < 2; ++pass) {
        int nloc = pass * 128 + g;
        int gnode = gn0 + nloc;
        if (gnode >= N_NODES) continue;
        const int o0 = off[nloc];
        const int dg = cnt[nloc];
        float a0 = 0.f, a1 = 0.f, a2 = 0.f, a3 = 0.f;
        float a4 = 0.f, a5 = 0.f, a6 = 0.f, a7 = 0.f;
        int j = 0;
        for (; j + 1 < dg; j += 2) {
            int i0 = (int)sout[o0 + j];
            int i1 = (int)sout[o0 + j + 1];
            uint4 v0 = *(const uint4*)&hc[(size_t)i0 * 64];
            uint4 v1 = *(const uint4*)&hc[(size_t)i1 * 64];
            a0 += __uint_as_float(v0.x << 16); a1 += __uint_as_float(v0.x & 0xffff0000u);
            a2 += __uint_as_float(v0.y << 16); a3 += __uint_as_float(v0.y & 0xffff0000u);
            a4 += __uint_as_float(v0.z << 16); a5 += __uint_as_float(v0.z & 0xffff0000u);
            a6 += __uint_as_float(v0.w << 16); a7 += __uint_as_float(v0.w & 0xffff0000u);
            a0 += __uint_as_float(v1.x << 16); a1 += __uint_as_float(v1.x & 0xffff0000u);
            a2 += __uint_as_float(v1.y << 16); a3 += __uint_as_float(v1.y & 0xffff0000u);
            a4 += __uint_as_float(v1.z << 16); a5 += __uint_as_float(v1.z & 0xffff0000u);
            a6 += __uint_as_float(v1.w << 16); a7 += __uint_as_float(v1.w & 0xffff0000u);
        }
        if (j < dg) {
            int i0 = (int)sout[o0 + j];
            uint4 v0 = *(const uint4*)&hc[(size_t)i0 * 64];
            a0 += __uint_as_float(v0.x << 16); a1 += __uint_as_float(v0.x & 0xffff0000u);
            a2 += __uint_as_float(v0.y << 16); a3 += __uint_as_float(v0.y & 0xffff0000u);
            a4 += __uint_as_float(v0.z << 16); a5 += __uint_as_float(v0.z & 0xffff0000u);
            a6 += __uint_as_float(v0.w << 16); a7 += __uint_as_float(v0.w & 0xffff0000u);
        }
        const float inv = 1.0f / (float)max(dg, 1);
        uint4 ov = *(const uint4*)&hc[(size_t)gnode * 64];
        float x0 = fmaf(a0, inv, __uint_as_float(ov.x << 16));
        float x1 = fmaf(a1, inv, __uint_as_float(ov.x & 0xffff0000u));
        float x2 = fmaf(a2, inv, __uint_as_float(ov.y << 16));
        float x3 = fmaf(a3, inv, __uint_as_float(ov.y & 0xffff0000u));
        float x4 = fmaf(a4, inv, __uint_as_float(ov.z << 16));
        float x5 = fmaf(a5, inv, __uint_as_float(ov.z & 0xffff0000u));
        float x6 = fmaf(a6, inv, __uint_as_float(ov.w << 16));
        float x7 = fmaf(a7, inv, __uint_as_float(ov.w & 0xffff0000u));
        uint4 o;
        o.x = (unsigned)f2bf(x0) | ((unsigned)f2bf(x1) << 16);
        o.y = (unsigned)f2bf(x2) | ((unsigned)f2bf(x3) << 16);
        o.z = (unsigned)f2bf(x4) | ((unsigned)f2bf(x5) << 16);
        o.w = (unsigned)f2bf(x6) | ((unsigned)f2bf(x7) << 16);
        *(uint4*)&xb[(size_t)gnode * 64 + ((c ^ (gnode & 7)) << 3)] = o;
    }
}

// weight prep (chunk-swizzled) + xb pad zero + h -> bf16 hb conversion
__global__ __launch_bounds__(256) void k_wprep(const float* __restrict__ W1,
                                               const float* __restrict__ W2,
                                               const float* __restrict__ h,
                                               unsigned short* __restrict__ w1t,
                                               unsigned short* __restrict__ w2t,
                                               unsigned short* __restrict__ xb,
                                               unsigned short* __restrict__ hb) {
    int id = blockIdx.x * 256 + threadIdx.x;     // 3261*256 = 834816
    if (id < 16384) {                            // n*64+k
        int n = id >> 6, k = id & 63;
        int dstp = (n << 6) + ((((k >> 3) ^ (n & 7))) << 3) + (k & 7);
        w1t[dstp] = f2bf(W1[k * 256 + n]);
    } else if (id < 32768) {
        int i2 = id - 16384;                     // d*256+k2
        int d = i2 >> 8, k2 = i2 & 255;
        int dstp = (d << 8) + ((((k2 >> 3) ^ (d & 7))) << 3) + (k2 & 7);
        w2t[dstp] = f2bf(W2[k2 * 64 + d]);
    } else if (id < 34816) {                     // zero 32 pad rows of xb
        xb[100000 * 64 + (id - 32768)] = 0;
    } else {                                     // h -> bf16, 8 elems/thread
        int i = id - 34816;                      // < 800000
        int e = i * 8;
        float4 f0 = *(const float4*)&h[e];
        float4 f1 = *(const float4*)&h[e + 4];
        uint4 o;
        o.x = (unsigned)f2bf(f0.x) | ((unsigned)f2bf(f0.y) << 16);
        o.y = (unsigned)f2bf(f0.z) | ((unsigned)f2bf(f0.w) << 16);
        o.z = (unsigned)f2bf(f1.x) | ((unsigned)f2bf(f1.y) << 16);
        o.w = (unsigned)f2bf(f1.z) | ((unsigned)f2bf(f1.w) << 16);
        *(uint4*)&hb[e] = o;
    }
}

// ---------------------------------------------------------------------------
// Fused MLP core (unchanged, verified at r3)
// ---------------------------------------------------------------------------
__device__ __forceinline__ void mlp_tile(const unsigned short* sXw,
                                         const unsigned short* sW1,
                                         const unsigned short* sW2,
                                         unsigned short* sHw,
                                         const float* sB1,
                                         int l15, int g4, int s7,
                                         f32x4 oacc[4]) {
    bf16x8 xf0 = *(const bf16x8*)&sXw[l15 * 64 + ((g4 ^ s7) << 3)];
    bf16x8 xf1 = *(const bf16x8*)&sXw[l15 * 64 + (((g4 + 4) ^ s7) << 3)];
#pragma unroll
    for (int dt = 0; dt < 4; ++dt) oacc[dt] = (f32x4){0.f, 0.f, 0.f, 0.f};

#pragma unroll
    for (int p = 0; p < 4; ++p) {
#pragma unroll
        for (int nt2 = 0; nt2 < 4; ++nt2) {
            const int n0 = p * 64 + nt2 * 16;
            f32x4 hacc = (f32x4){0.f, 0.f, 0.f, 0.f};
            bf16x8 wf0 = *(const bf16x8*)&sW1[(n0 + l15) * 64 + ((g4 ^ s7) << 3)];
            bf16x8 wf1 = *(const bf16x8*)&sW1[(n0 + l15) * 64 + (((g4 + 4) ^ s7) << 3)];
            hacc = __builtin_amdgcn_mfma_f32_16x16x32_bf16(wf0, xf0, hacc, 0, 0, 0);
            hacc = __builtin_amdgcn_mfma_f32_16x16x32_bf16(wf1, xf1, hacc, 0, 0, 0);
            float4 bq = *(const float4*)&sB1[n0 + g4 * 4];
            ushort4 pk;
            pk.x = f2bf(fmaxf(hacc[0] + bq.x, 0.f));
            pk.y = f2bf(fmaxf(hacc[1] + bq.y, 0.f));
            pk.z = f2bf(fmaxf(hacc[2] + bq.z, 0.f));
            pk.w = f2bf(fmaxf(hacc[3] + bq.w, 0.f));
            int qh = nt2 * 2 + (g4 >> 1);
            *(ushort4*)&sHw[l15 * 64 + ((qh ^ s7) << 3) + ((g4 & 1) << 2)] = pk;
        }
#pragma unroll
        for (int s2 = 0; s2 < 2; ++s2) {
            bf16x8 a2 = *(const bf16x8*)&sHw[l15 * 64 + (((s2 * 4 + g4) ^ s7) << 3)];
#pragma unroll
            for (int dt = 0; dt < 4; ++dt) {
                int q = p * 8 + s2 * 4 + g4;
                bf16x8 w2f = *(const bf16x8*)&sW2[(dt * 16 + l15) * 256 + ((q ^ s7) << 3)];
                oacc[dt] = __builtin_amdgcn_mfma_f32_16x16x32_bf16(a2, w2f, oacc[dt], 0, 0, 0);
            }
        }
    }
}

// single-pass MLP + BN (grid barrier; all 256 blocks co-resident)
__global__ __launch_bounds__(512, 2) void k_mlpf(const unsigned short* __restrict__ xb,
                                                 const unsigned short* __restrict__ w1t,
                                                 const unsigned short* __restrict__ w2t,
                                                 const float* __restrict__ b1,
                                                 const float* __restrict__ b2,
                                                 const float* __restrict__ gamma,
                                                 const float* __restrict__ beta,
                                                 float* __restrict__ stats,
                                                 int* __restrict__ bar,
                                                 float* __restrict__ out,
                                                 float* __restrict__ dump) {
    __shared__ unsigned short sW1[256 * 64];
    __shared__ unsigned short sW2[64 * 256];
    __shared__ unsigned short sH[8][16 * 64];
    __shared__ unsigned short sX[8][2][16 * 64];
    __shared__ float sB1[256];
    const int t = threadIdx.x;
    const int lane = t & 63;
    const int w = t >> 6;
    const int l15 = lane & 15;
    const int g4 = lane >> 4;
    const int s7 = l15 & 7;
    const int bid = blockIdx.x;

    for (int i = t; i < 2048; i += 512)
        *(uint4*)&sW1[i * 8] = *(const uint4*)&w1t[i * 8];
    for (int i = t; i < 2048; i += 512)
        *(uint4*)&sW2[i * 8] = *(const uint4*)&w2t[i * 8];
    if (t < 256) sB1[t] = b1[t];
    __syncthreads();

    float b2v[4];
#pragma unroll
    for (int dt = 0; dt < 4; ++dt) b2v[dt] = b2[dt * 16 + l15];

    float lsum[4] = {0.f, 0.f, 0.f, 0.f};
    float lsq[4]  = {0.f, 0.f, 0.f, 0.f};
    f32x4 osave[MAXIT][4];

    int cur = 0;
    {
        int r0 = min(bid * 128 + w * 16, XBROWS - 16);
        stage_issue(xb + (size_t)r0 * 64 + lane * 8, &sX[w][0][0]);
    }
#pragma unroll
    for (int it = 0; it < MAXIT; ++it) {
        int gp = bid + it * MLPGRID;
        int gpn = gp + MLPGRID; if (gpn >= NGP) gpn = gp;
        int r0n = min(gpn * 128 + w * 16, XBROWS - 16);
        stage_issue(xb + (size_t)r0n * 64 + lane * 8, &sX[w][cur ^ 1][0]);
        WAITV(2);
        __builtin_amdgcn_sched_barrier(0);
        const int row0 = gp * 128 + w * 16;
        if (gp < NGP && row0 < XBROWS) {
            f32x4 oacc[4];
            mlp_tile(&sX[w][cur][0], sW1, sW2, &sH[w][0], sB1, l15, g4, s7, oacc);
#pragma unroll
            for (int dt = 0; dt < 4; ++dt) {
#pragma unroll
                for (int r = 0; r < 4; ++r) {
                    float val = fmaxf(oacc[dt][r] + b2v[dt], 0.f);
                    osave[it][dt][r] = val;
                    int mabs = row0 + g4 * 4 + r;
                    if (mabs < N_NODES) {
                        lsum[dt] += val;
                        lsq[dt] += val * val;
                    }
                }
            }
        }
        cur ^= 1;
    }

    // block-level stats reduction (reuse sW1 memory)
    __syncthreads();
    float* sred = (float*)&sW1[0];                // [512][8] = 16 KB
#pragma unroll
    for (int dt = 0; dt < 4; ++dt) {
        sred[t * 8 + dt] = lsum[dt];
        sred[t * 8 + 4 + dt] = lsq[dt];
    }
    __syncthreads();
    if (t < 128) {
        int issq = (t >= 64) ? 4 : 0;
        int d = t & 63;
        int dt = d >> 4, dl = d & 15;
        float acc = 0.f;
        for (int i = 0; i < 32; ++i) acc += sred[(dl + 16 * i) * 8 + issq + dt];
        atomicAdd(&stats[(issq ? 64 : 0) + d], acc);
    }

    // software grid barrier
    __syncthreads();
    if (t == 0) {
        __hip_atomic_fetch_add(bar, 1, __ATOMIC_ACQ_REL, __HIP_MEMORY_SCOPE_AGENT);
        while (__hip_atomic_load(bar, __ATOMIC_ACQUIRE, __HIP_MEMORY_SCOPE_AGENT)
               < MLPGRID)
            __builtin_amdgcn_s_sleep(4);
    }
    __syncthreads();

    float scv[4], shv[4];
    const float inv_n = 1.0f / (float)N_NODES;
#pragma unroll
    for (int dt = 0; dt < 4; ++dt) {
        int d = dt * 16 + l15;
        float sm = __hip_atomic_load(&stats[d], __ATOMIC_RELAXED,
                                     __HIP_MEMORY_SCOPE_AGENT);
        float sq = __hip_atomic_load(&stats[64 + d], __ATOMIC_RELAXED,
                                     __HIP_MEMORY_SCOPE_AGENT);
        float m = sm * inv_n;
        float v = sq * inv_n - m * m;
        float sc = gamma[d] * rsqrtf(v + BN_EPS);
        scv[dt] = sc;
        shv[dt] = beta[d] - m * sc;
    }

#pragma unroll
    for (int it = 0; it < MAXIT; ++it) {
        int gp = bid + it * MLPGRID;
        const int row0 = gp * 128 + w * 16;
        if (gp >= NGP || row0 >= XBROWS) continue;
        float* sHf = (float*)&sH[w][0];           // [8][64] f32 = 2048 B
#pragma unroll
        for (int hh = 0; hh < 2; ++hh) {
            asm volatile("" ::: "memory");
            if ((g4 >> 1) == hh) {
#pragma unroll
                for (int dt = 0; dt < 4; ++dt) {
#pragma unroll
                    for (int r = 0; r < 4; ++r) {
                        float val = fmaf(osave[it][dt][r], scv[dt], shv[dt]);
                        sHf[((g4 & 1) * 4 + r) * 64 + dt * 16 + l15] = val;
                    }
                }
            }
            asm volatile("" ::: "memory");
#pragma unroll
            for (int j = 0; j < 2; ++j) {
                int rl = j * 4 + (lane >> 4);
                int rg = row0 + hh * 8 + rl;
                float4 v = *(const float4*)&sHf[rl * 64 + (lane & 15) * 4];
                float* dstp = (rg < N_NODES)
                    ? &out[(size_t)rg * 64 + (lane & 15) * 4]
                    : &dump[lane * 4];
                *(float4*)dstp = v;
            }
        }
    }
}

extern "C" void kernel_launch(void* const* d_in, const int* in_sizes, int n_in,
                              void* d_out, int out_size, void* d_ws, size_t ws_size,
                              hipStream_t stream) {
    const float* h     = (const float*)d_in[0];
    const float* W1    = (const float*)d_in[1];
    const float* b1    = (const float*)d_in[2];
    const float* W2    = (const float*)d_in[3];
    const float* b2    = (const float*)d_in[4];
    const float* gamma = (const float*)d_in[5];
    const float* beta  = (const float*)d_in[6];
    const int*   src   = (const int*)d_in[7];
    const int*   dst   = (const int*)d_in[8];

    int* wsi = (int*)d_ws;
    float*          stats  = (float*)wsi;                          // 128
    int*            bar    = wsi + 128;                            // 128
    int*            runoff = wsi + 256;                            // 200704
    float*          dump   = (float*)(wsi + 256);                  // alias (dead)
    unsigned short* w1t    = (unsigned short*)(wsi + 200960);      // 8192 ints
    unsigned short* w2t    = (unsigned short*)(wsi + 209152);      // 8192 ints
    unsigned short* xb     = (unsigned short*)(wsi + 217344);      // 3201024 ints
    unsigned int*   ebuf   = (unsigned int*)(wsi + 3418368);       // 1600000
    unsigned short* hb     = (unsigned short*)(wsi + 5018368);     // 3200000 ints
    float*          out    = (float*)d_out;

    // zero stats + bar
    hipMemsetAsync(wsi, 0, 1024, stream);

    kA_scatter<<<SBLK, 1024, 0, stream>>>(src, dst, ebuf, runoff);
    k_wprep<<<3261, 256, 0, stream>>>(W1, W2, h, w1t, w2t, xb, hb);
    kB_fused<<<NBUCK, 1024, 0, stream>>>(ebuf, runoff, hb, xb);
    k_mlpf<<<MLPGRID, 512, 0, stream>>>(xb, w1t, w2t, b1, b2, gamma, beta,
                                        stats, bar, out, dump);
}

// Round 6
// 172.202 us; speedup vs baseline: 4.8262x; 1.0225x over previous
//
#include <hip/hip_runtime.h>

#define N_NODES 100000
#define N_EDGES 1600000
#define DIM     64
#define HID     256
#define BN_EPS  1e-5f

// counting-sort parameters
#define NBUCK   391            // ceil(100000/256) buckets of 256 nodes
#define RSTRIDE 392            // runoff row stride (NBUCK + 1 for chunk total)
#define SCHUNK  3125           // edges per kA_scatter block
#define SBLK    512            // 512 * 3125 = 1,600,000 exactly
#define MAXB    6144           // max edges per bucket (mean 4096, sd 64 -> +32 sd)

// MLP parameters
#define XBROWS  100032         // padded xb rows
#define NGP     782            // ceil(100032/128) block-iterations of 128 rows
#define MLPGRID 256            // 1 block/CU (LDS-forced); grid == CU count
#define MAXIT   4              // ceil(NGP/MLPGRID)

typedef short bf16x8 __attribute__((ext_vector_type(8)));
typedef float f32x4  __attribute__((ext_vector_type(4)));

// ws layout (4-byte units):
//   stats   float[128]         @ 0        (sum[64], sumsq[64])   [zeroed by kA blk34]
//   bar     int[128]           @ 128      (grid barrier)         [zeroed by kA blk34]
//   runoff  int[512*392]       @ 256      (200704; dead after kB_fused -> dump)
//   w1t_g   bf16[256*64]       @ 200960   (8192 ints) [n][k] chunk-swizzled
//   w2t_g   bf16[64*256]       @ 209152   (8192 ints) [d][k2] chunk-swizzled
//   xb      bf16[100032*64]    @ 217344   (3201024 ints, 16B aligned)
//   ebuf    u32[1600000]       @ 3418368
//   hb      bf16[100000*64]    @ 5018368  (3200000 ints) h in bf16 row-major

// native bf16 convert (RNE): compiler emits v_cvt_pk_bf16_f32 for adjacent pairs
__device__ __forceinline__ unsigned short f2bf(float x) {
    union { __bf16 b; unsigned short u; } cv;
    cv.b = (__bf16)x;
    return cv.u;
}
__device__ __forceinline__ unsigned pk2(float a, float b) {
    return (unsigned)f2bf(a) | ((unsigned)f2bf(b) << 16);
}

#define WAITV(N) asm volatile("s_waitcnt vmcnt(" #N ")" ::: "memory")

// issue 2x global_load_lds(16B) staging 16 rows (2048 B) into per-wave LDS buffer.
__device__ __forceinline__ void stage_issue(const unsigned short* gsrc,
                                            unsigned short* ldst) {
    __builtin_amdgcn_global_load_lds(
        (const __attribute__((address_space(1))) void*)gsrc,
        (__attribute__((address_space(3))) void*)ldst, 16, 0, 0);
    __builtin_amdgcn_global_load_lds(
        (const __attribute__((address_space(1))) void*)(gsrc + 512),
        (__attribute__((address_space(3))) void*)(ldst + 512), 16, 0, 0);
}

// ---------------------------------------------------------------------------
// Pass A: per-chunk LDS counting sort by coarse bucket (dst>>8)
// + fused prep epilogue: h->bf16 hb (all blocks), weight transpose+swizzle
//   (blocks 0..33, 1 elem/thread), xb pad zero, stats/bar zero (block 34).
// ---------------------------------------------------------------------------
__global__ __launch_bounds__(1024) void kA_scatter(const int* __restrict__ src,
                                                   const int* __restrict__ dst,
                                                   const float* __restrict__ h,
                                                   const float* __restrict__ W1,
                                                   const float* __restrict__ W2,
                                                   unsigned int* __restrict__ ebuf,
                                                   int* __restrict__ runoff,
                                                   unsigned short* __restrict__ w1t,
                                                   unsigned short* __restrict__ w2t,
                                                   unsigned short* __restrict__ xb,
                                                   unsigned short* __restrict__ hb,
                                                   int* __restrict__ statsbar) {
    __shared__ int hist[NBUCK];
    __shared__ int ebase[NBUCK];
    __shared__ int sc[512];
    __shared__ unsigned int stage[SCHUNK];
    const int t = threadIdx.x;
    const int e0 = blockIdx.x * SCHUNK;
    const int n = SCHUNK;                         // exact partition

    for (int i = t; i < NBUCK; i += 1024) hist[i] = 0;
    __syncthreads();
    for (int i = t; i < n; i += 1024)
        atomicAdd(&hist[dst[e0 + i] >> 8], 1);    // int LDS atomic: native ds op
    __syncthreads();

    if (t < 512) sc[t] = (t < NBUCK) ? hist[t] : 0;
    __syncthreads();
    for (int off = 1; off < 512; off <<= 1) {
        int add = (t < 512 && t >= off) ? sc[t - off] : 0;
        __syncthreads();
        if (t < 512) sc[t] += add;
        __syncthreads();
    }
    if (t < NBUCK) {
        int ex = sc[t] - hist[t];
        ebase[t] = ex;
        runoff[blockIdx.x * RSTRIDE + t] = ex;
    }
    if (t == 0) runoff[blockIdx.x * RSTRIDE + NBUCK] = n;
    if (t < NBUCK) hist[t] = 0;
    __syncthreads();

    for (int i = t; i < n; i += 1024) {
        int d = dst[e0 + i];
        int s = src[e0 + i];
        int b = d >> 8;
        int r = atomicAdd(&hist[b], 1);
        stage[ebase[b] + r] = ((unsigned int)s << 8) | (unsigned int)(d & 255);
    }
    __syncthreads();
    for (int i = t; i < n; i += 1024)
        ebuf[e0 + i] = stage[i];

    // ---- fused prep epilogue (no LDS, no barriers needed) ----
    // h -> bf16 hb, 8 elems per item, grid-strided over all blocks
    for (int i = blockIdx.x * 1024 + t; i < 800000; i += SBLK * 1024) {
        int e = i * 8;
        float4 f0 = *(const float4*)&h[e];
        float4 f1 = *(const float4*)&h[e + 4];
        uint4 o;
        o.x = pk2(f0.x, f0.y);
        o.y = pk2(f0.z, f0.w);
        o.z = pk2(f1.x, f1.y);
        o.w = pk2(f1.z, f1.w);
        *(uint4*)&hb[e] = o;
    }
    // weights (chunk-swizzled) + xb pad, 1 elem/thread on blocks 0..33
    int id = blockIdx.x * 1024 + t;
    if (id < 16384) {                            // w1t: n*64+k
        int nn = id >> 6, k = id & 63;
        int dstp = (nn << 6) + ((((k >> 3) ^ (nn & 7))) << 3) + (k & 7);
        w1t[dstp] = f2bf(W1[k * 256 + nn]);
    } else if (id < 32768) {                     // w2t: d*256+k2
        int i2 = id - 16384;
        int d = i2 >> 8, k2 = i2 & 255;
        int dstp = (d << 8) + ((((k2 >> 3) ^ (d & 7))) << 3) + (k2 & 7);
        w2t[dstp] = f2bf(W2[k2 * 64 + d]);
    } else if (id < 34816) {                     // zero 32 pad rows of xb
        xb[100000 * 64 + (id - 32768)] = 0;
    }
    // zero stats + bar (256 ints), block 34
    if (blockIdx.x == 34 && t < 256) statsbar[t] = 0;
}

// ---------------------------------------------------------------------------
// Pass B (fused, register-accumulate): one block per bucket.
// 1) thread-per-run copy of bucket edges -> stage2 (LDS) + degree histogram
// 2) per-node offsets via LDS scan; sort src ids into sout (int LDS atomics)
// 3) 8-lane group per node: walk contiguous sout segment, gather hb rows,
//    register-accumulate, emit xb = acc/max(deg,1)+own (swizzled bf16 row).
// ---------------------------------------------------------------------------
__global__ __launch_bounds__(1024) void kB_fused(const unsigned int* __restrict__ ebuf,
                                                 const int* __restrict__ runoff,
                                                 const unsigned short* __restrict__ hb,
                                                 unsigned short* __restrict__ xb) {
    __shared__ int runbase[SBLK + 1];
    __shared__ int sc[SBLK];
    __shared__ int cnt[256];
    __shared__ int off[256];
    __shared__ unsigned int stage2[MAXB];
    __shared__ unsigned int sout[MAXB];
    const int t = threadIdx.x;
    const int b = blockIdx.x;

    int rl = 0, rs = 0;
    if (t < SBLK) {
        int s = runoff[t * RSTRIDE + b];
        int e = runoff[t * RSTRIDE + b + 1];
        rs = t * SCHUNK + s;
        rl = e - s;
        sc[t] = rl;
    }
    if (t < 256) cnt[t] = 0;
    __syncthreads();
    for (int o = 1; o < SBLK; o <<= 1) {
        int add = (t < SBLK && t >= o) ? sc[t - o] : 0;
        __syncthreads();
        if (t < SBLK) sc[t] += add;
        __syncthreads();
    }
    if (t == 0) runbase[SBLK] = sc[SBLK - 1];
    __syncthreads();
    const int total = min(runbase[SBLK], MAXB);

    // thread-per-run copy into LDS + degree histogram (no binary search)
    if (t < SBLK && rl > 0) {
        int base = sc[t] - rl;
        int lim = min(rl, MAXB - base);
        for (int k = 0; k < lim; ++k) {
            unsigned int v = ebuf[rs + k];
            stage2[base + k] = v;
            atomicAdd(&cnt[v & 255u], 1);
        }
    }
    __syncthreads();

    // per-node exclusive offsets within the bucket
    int c0 = (t < 256) ? cnt[t] : 0;
    if (t < 256) sc[t] = c0;
    __syncthreads();
    for (int o = 1; o < 256; o <<= 1) {
        int add = (t < 256 && t >= o) ? sc[t - o] : 0;
        __syncthreads();
        if (t < 256) sc[t] += add;
        __syncthreads();
    }
    if (t < 256) { off[t] = sc[t] - c0; cnt[t] = 0; }
    __syncthreads();

    // sort src ids by node into sout (contiguous per-node segments)
    for (int idx = t; idx < total; idx += 1024) {
        unsigned int v = stage2[idx];
        int node = (int)(v & 255u);
        int r = atomicAdd(&cnt[node], 1);
        sout[off[node] + r] = v >> 8;
    }
    __syncthreads();

    // aggregate: 8-lane group per node; lane c covers dims c*8..c*8+7.
    const int g = t >> 3, c = t & 7;
    const unsigned short* hc = hb + c * 8;
    const int gn0 = b * 256;
#pragma unroll
    for (int pass = 0; pass < 2; ++pass) {
        int nloc = pass * 128 + g;
        int gnode = gn0 + nloc;
        if (gnode >= N_NODES) continue;
        const int o0 = off[nloc];
        const int dg = cnt[nloc];
        float a0 = 0.f, a1 = 0.f, a2 = 0.f, a3 = 0.f;
        float a4 = 0.f, a5 = 0.f, a6 = 0.f, a7 = 0.f;
        int j = 0;
        for (; j + 1 < dg; j += 2) {
            int i0 = (int)sout[o0 + j];
            int i1 = (int)sout[o0 + j + 1];
            uint4 v0 = *(const uint4*)&hc[(size_t)i0 * 64];
            uint4 v1 = *(const uint4*)&hc[(size_t)i1 * 64];
            a0 += __uint_as_float(v0.x << 16); a1 += __uint_as_float(v0.x & 0xffff0000u);
            a2 += __uint_as_float(v0.y << 16); a3 += __uint_as_float(v0.y & 0xffff0000u);
            a4 += __uint_as_float(v0.z << 16); a5 += __uint_as_float(v0.z & 0xffff0000u);
            a6 += __uint_as_float(v0.w << 16); a7 += __uint_as_float(v0.w & 0xffff0000u);
            a0 += __uint_as_float(v1.x << 16); a1 += __uint_as_float(v1.x & 0xffff0000u);
            a2 += __uint_as_float(v1.y << 16); a3 += __uint_as_float(v1.y & 0xffff0000u);
            a4 += __uint_as_float(v1.z << 16); a5 += __uint_as_float(v1.z & 0xffff0000u);
            a6 += __uint_as_float(v1.w << 16); a7 += __uint_as_float(v1.w & 0xffff0000u);
        }
        if (j < dg) {
            int i0 = (int)sout[o0 + j];
            uint4 v0 = *(const uint4*)&hc[(size_t)i0 * 64];
            a0 += __uint_as_float(v0.x << 16); a1 += __uint_as_float(v0.x & 0xffff0000u);
            a2 += __uint_as_float(v0.y << 16); a3 += __uint_as_float(v0.y & 0xffff0000u);
            a4 += __uint_as_float(v0.z << 16); a5 += __uint_as_float(v0.z & 0xffff0000u);
            a6 += __uint_as_float(v0.w << 16); a7 += __uint_as_float(v0.w & 0xffff0000u);
        }
        const float inv = 1.0f / (float)max(dg, 1);
        uint4 ov = *(const uint4*)&hc[(size_t)gnode * 64];
        float x0 = fmaf(a0, inv, __uint_as_float(ov.x << 16));
        float x1 = fmaf(a1, inv, __uint_as_float(ov.x & 0xffff0000u));
        float x2 = fmaf(a2, inv, __uint_as_float(ov.y << 16));
        float x3 = fmaf(a3, inv, __uint_as_float(ov.y & 0xffff0000u));
        float x4 = fmaf(a4, inv, __uint_as_float(ov.z << 16));
        float x5 = fmaf(a5, inv, __uint_as_float(ov.z & 0xffff0000u));
        float x6 = fmaf(a6, inv, __uint_as_float(ov.w << 16));
        float x7 = fmaf(a7, inv, __uint_as_float(ov.w & 0xffff0000u));
        uint4 o;
        o.x = pk2(x0, x1);
        o.y = pk2(x2, x3);
        o.z = pk2(x4, x5);
        o.w = pk2(x6, x7);
        *(uint4*)&xb[(size_t)gnode * 64 + ((c ^ (gnode & 7)) << 3)] = o;
    }
}

// ---------------------------------------------------------------------------
// Fused MLP core (structure verified at r3; bf16 converts now native cvt_pk)
// ---------------------------------------------------------------------------
__device__ __forceinline__ void mlp_tile(const unsigned short* sXw,
                                         const unsigned short* sW1,
                                         const unsigned short* sW2,
                                         unsigned short* sHw,
                                         const float* sB1,
                                         int l15, int g4, int s7,
                                         f32x4 oacc[4]) {
    bf16x8 xf0 = *(const bf16x8*)&sXw[l15 * 64 + ((g4 ^ s7) << 3)];
    bf16x8 xf1 = *(const bf16x8*)&sXw[l15 * 64 + (((g4 + 4) ^ s7) << 3)];
#pragma unroll
    for (int dt = 0; dt < 4; ++dt) oacc[dt] = (f32x4){0.f, 0.f, 0.f, 0.f};

#pragma unroll
    for (int p = 0; p < 4; ++p) {
#pragma unroll
        for (int nt2 = 0; nt2 < 4; ++nt2) {
            const int n0 = p * 64 + nt2 * 16;
            f32x4 hacc = (f32x4){0.f, 0.f, 0.f, 0.f};
            bf16x8 wf0 = *(const bf16x8*)&sW1[(n0 + l15) * 64 + ((g4 ^ s7) << 3)];
            bf16x8 wf1 = *(const bf16x8*)&sW1[(n0 + l15) * 64 + (((g4 + 4) ^ s7) << 3)];
            hacc = __builtin_amdgcn_mfma_f32_16x16x32_bf16(wf0, xf0, hacc, 0, 0, 0);
            hacc = __builtin_amdgcn_mfma_f32_16x16x32_bf16(wf1, xf1, hacc, 0, 0, 0);
            float4 bq = *(const float4*)&sB1[n0 + g4 * 4];
            ushort2 pkl, pkh;
            unsigned plo = pk2(fmaxf(hacc[0] + bq.x, 0.f),
                               fmaxf(hacc[1] + bq.y, 0.f));
            unsigned phi = pk2(fmaxf(hacc[2] + bq.z, 0.f),
                               fmaxf(hacc[3] + bq.w, 0.f));
            int qh = nt2 * 2 + (g4 >> 1);
            uint2 pk = {plo, phi};
            *(uint2*)&sHw[l15 * 64 + ((qh ^ s7) << 3) + ((g4 & 1) << 2)] = pk;
        }
#pragma unroll
        for (int s2 = 0; s2 < 2; ++s2) {
            bf16x8 a2 = *(const bf16x8*)&sHw[l15 * 64 + (((s2 * 4 + g4) ^ s7) << 3)];
#pragma unroll
            for (int dt = 0; dt < 4; ++dt) {
                int q = p * 8 + s2 * 4 + g4;
                bf16x8 w2f = *(const bf16x8*)&sW2[(dt * 16 + l15) * 256 + ((q ^ s7) << 3)];
                oacc[dt] = __builtin_amdgcn_mfma_f32_16x16x32_bf16(a2, w2f, oacc[dt], 0, 0, 0);
            }
        }
    }
}

// single-pass MLP + BN (grid barrier; all 256 blocks co-resident)
__global__ __launch_bounds__(512, 2) void k_mlpf(const unsigned short* __restrict__ xb,
                                                 const unsigned short* __restrict__ w1t,
                                                 const unsigned short* __restrict__ w2t,
                                                 const float* __restrict__ b1,
                                                 const float* __restrict__ b2,
                                                 const float* __restrict__ gamma,
                                                 const float* __restrict__ beta,
                                                 float* __restrict__ stats,
                                                 int* __restrict__ bar,
                                                 float* __restrict__ out,
                                                 float* __restrict__ dump) {
    __shared__ unsigned short sW1[256 * 64];
    __shared__ unsigned short sW2[64 * 256];
    __shared__ unsigned short sH[8][16 * 64];
    __shared__ unsigned short sX[8][2][16 * 64];
    __shared__ float sB1[256];
    const int t = threadIdx.x;
    const int lane = t & 63;
    const int w = t >> 6;
    const int l15 = lane & 15;
    const int g4 = lane >> 4;
    const int s7 = l15 & 7;
    const int bid = blockIdx.x;

    for (int i = t; i < 2048; i += 512)
        *(uint4*)&sW1[i * 8] = *(const uint4*)&w1t[i * 8];
    for (int i = t; i < 2048; i += 512)
        *(uint4*)&sW2[i * 8] = *(const uint4*)&w2t[i * 8];
    if (t < 256) sB1[t] = b1[t];
    __syncthreads();

    float b2v[4];
#pragma unroll
    for (int dt = 0; dt < 4; ++dt) b2v[dt] = b2[dt * 16 + l15];

    float lsum[4] = {0.f, 0.f, 0.f, 0.f};
    float lsq[4]  = {0.f, 0.f, 0.f, 0.f};
    f32x4 osave[MAXIT][4];

    int cur = 0;
    {
        int r0 = min(bid * 128 + w * 16, XBROWS - 16);
        stage_issue(xb + (size_t)r0 * 64 + lane * 8, &sX[w][0][0]);
    }
#pragma unroll
    for (int it = 0; it < MAXIT; ++it) {
        int gp = bid + it * MLPGRID;
        int gpn = gp + MLPGRID; if (gpn >= NGP) gpn = gp;
        int r0n = min(gpn * 128 + w * 16, XBROWS - 16);
        stage_issue(xb + (size_t)r0n * 64 + lane * 8, &sX[w][cur ^ 1][0]);
        WAITV(2);
        __builtin_amdgcn_sched_barrier(0);
        const int row0 = gp * 128 + w * 16;
        if (gp < NGP && row0 < XBROWS) {
            f32x4 oacc[4];
            mlp_tile(&sX[w][cur][0], sW1, sW2, &sH[w][0], sB1, l15, g4, s7, oacc);
#pragma unroll
            for (int dt = 0; dt < 4; ++dt) {
#pragma unroll
                for (int r = 0; r < 4; ++r) {
                    float val = fmaxf(oacc[dt][r] + b2v[dt], 0.f);
                    osave[it][dt][r] = val;
                    int mabs = row0 + g4 * 4 + r;
                    if (mabs < N_NODES) {
                        lsum[dt] += val;
                        lsq[dt] += val * val;
                    }
                }
            }
        }
        cur ^= 1;
    }

    // block-level stats reduction (reuse sW1 memory)
    __syncthreads();
    float* sred = (float*)&sW1[0];                // [512][8] = 16 KB
#pragma unroll
    for (int dt = 0; dt < 4; ++dt) {
        sred[t * 8 + dt] = lsum[dt];
        sred[t * 8 + 4 + dt] = lsq[dt];
    }
    __syncthreads();
    if (t < 128) {
        int issq = (t >= 64) ? 4 : 0;
        int d = t & 63;
        int dt = d >> 4, dl = d & 15;
        float acc = 0.f;
        for (int i = 0; i < 32; ++i) acc += sred[(dl + 16 * i) * 8 + issq + dt];
        atomicAdd(&stats[(issq ? 64 : 0) + d], acc);
    }

    // software grid barrier
    __syncthreads();
    if (t == 0) {
        __hip_atomic_fetch_add(bar, 1, __ATOMIC_ACQ_REL, __HIP_MEMORY_SCOPE_AGENT);
        while (__hip_atomic_load(bar, __ATOMIC_ACQUIRE, __HIP_MEMORY_SCOPE_AGENT)
               < MLPGRID)
            __builtin_amdgcn_s_sleep(4);
    }
    __syncthreads();

    float scv[4], shv[4];
    const float inv_n = 1.0f / (float)N_NODES;
#pragma unroll
    for (int dt = 0; dt < 4; ++dt) {
        int d = dt * 16 + l15;
        float sm = __hip_atomic_load(&stats[d], __ATOMIC_RELAXED,
                                     __HIP_MEMORY_SCOPE_AGENT);
        float sq = __hip_atomic_load(&stats[64 + d], __ATOMIC_RELAXED,
                                     __HIP_MEMORY_SCOPE_AGENT);
        float m = sm * inv_n;
        float v = sq * inv_n - m * m;
        float sc = gamma[d] * rsqrtf(v + BN_EPS);
        scv[dt] = sc;
        shv[dt] = beta[d] - m * sc;
    }

#pragma unroll
    for (int it = 0; it < MAXIT; ++it) {
        int gp = bid + it * MLPGRID;
        const int row0 = gp * 128 + w * 16;
        if (gp >= NGP || row0 >= XBROWS) continue;
        float* sHf = (float*)&sH[w][0];           // [8][64] f32 = 2048 B
#pragma unroll
        for (int hh = 0; hh < 2; ++hh) {
            asm volatile("" ::: "memory");
            if ((g4 >> 1) == hh) {
#pragma unroll
                for (int dt = 0; dt < 4; ++dt) {
#pragma unroll
                    for (int r = 0; r < 4; ++r) {
                        float val = fmaf(osave[it][dt][r], scv[dt], shv[dt]);
                        sHf[((g4 & 1) * 4 + r) * 64 + dt * 16 + l15] = val;
                    }
                }
            }
            asm volatile("" ::: "memory");
#pragma unroll
            for (int j = 0; j < 2; ++j) {
                int rl = j * 4 + (lane >> 4);
                int rg = row0 + hh * 8 + rl;
                float4 v = *(const float4*)&sHf[rl * 64 + (lane & 15) * 4];
                float* dstp = (rg < N_NODES)
                    ? &out[(size_t)rg * 64 + (lane & 15) * 4]
                    : &dump[lane * 4];
                *(float4*)dstp = v;
            }
        }
    }
}

extern "C" void kernel_launch(void* const* d_in, const int* in_sizes, int n_in,
                              void* d_out, int out_size, void* d_ws, size_t ws_size,
                              hipStream_t stream) {
    const float* h     = (const float*)d_in[0];
    const float* W1    = (const float*)d_in[1];
    const float* b1    = (const float*)d_in[2];
    const float* W2    = (const float*)d_in[3];
    const float* b2    = (const float*)d_in[4];
    const float* gamma = (const float*)d_in[5];
    const float* beta  = (const float*)d_in[6];
    const int*   src   = (const int*)d_in[7];
    const int*   dst   = (const int*)d_in[8];

    int* wsi = (int*)d_ws;
    float*          stats   = (float*)wsi;                         // 128
    int*            bar     = wsi + 128;                           // 128
    int*            statsbar = wsi;                                // 256 ints
    int*            runoff  = wsi + 256;                           // 200704
    float*          dump    = (float*)(wsi + 256);                 // alias (dead)
    unsigned short* w1t     = (unsigned short*)(wsi + 200960);     // 8192 ints
    unsigned short* w2t     = (unsigned short*)(wsi + 209152);     // 8192 ints
    unsigned short* xb      = (unsigned short*)(wsi + 217344);     // 3201024 ints
    unsigned int*   ebuf    = (unsigned int*)(wsi + 3418368);      // 1600000
    unsigned short* hb      = (unsigned short*)(wsi + 5018368);    // 3200000 ints
    float*          out     = (float*)d_out;

    kA_scatter<<<SBLK, 1024, 0, stream>>>(src, dst, h, W1, W2, ebuf, runoff,
                                          w1t, w2t, xb, hb, statsbar);
    kB_fused<<<NBUCK, 1024, 0, stream>>>(ebuf, runoff, hb, xb);
    k_mlpf<<<MLPGRID, 512, 0, stream>>>(xb, w1t, w2t, b1, b2, gamma, beta,
                                        stats, bar, out, dump);
}